// Round 4
// baseline (1214.092 us; speedup 1.0000x reference)
//
#include <hip/hip_runtime.h>

#define N_NODES 100000
#define N_EDGES 1600000
#define NB 782      // ceil(N_NODES/128) buckets of 128 dst nodes
#define BSHIFT 7

// ws layout (bytes):
//  cnt   @ 0       : NB u32        (3128)   per-bucket edge counts
//  offs  @ 3200    : NB+1 u32      (3132)   bucket offsets
//  cur   @ 6400    : NB u32        (3128)   fill cursors
//  stats @ 9600    : 128 f64       (1024)   BN sum / sumsq
//  U     @ 10624   : 64x128 f32    (32768)  U[i][k*64+o] = sum_j linear[k][i][j]*mlp_w[o][j]
//  pay   @ 43392   : N_EDGES u32   (6.4MB)  packed (dst&127)<<18 | src<<1 | ord, bucket-sorted
//  B     @ 6443392 : N_NODES x 128 bf16 (25.6MB)  B[n][k*64+o] = feature[n] . U[:,k*64+o]

__device__ __forceinline__ unsigned short f2bf(float x) {
  unsigned u = __float_as_uint(x);
  unsigned r = (u + 0x7FFFu + ((u >> 16) & 1u)) >> 16;
  return (unsigned short)r;
}

__global__ __launch_bounds__(256) void prep_U(const float* __restrict__ linear,
                                              const float* __restrict__ mlp_w,
                                              float* __restrict__ U) {
  for (int idx = threadIdx.x; idx < 2 * 64 * 64; idx += 256) {
    int o = idx & 63;
    int ki = idx >> 6;  // k*64 + i
    int k = ki >> 6, i = ki & 63;
    float acc = 0.f;
#pragma unroll 8
    for (int j = 0; j < 64; ++j)
      acc += linear[ki * 64 + j] * mlp_w[o * 64 + j];
    U[i * 128 + k * 64 + o] = acc;
  }
}

// B = feature @ U, stored bf16
__global__ __launch_bounds__(256) void prep_B(const float* __restrict__ feature,
                                              const float* __restrict__ U,
                                              unsigned short* __restrict__ B) {
  __shared__ float Us[64 * 128];
  for (int i = threadIdx.x; i < 64 * 128; i += 256) Us[i] = U[i];
  __syncthreads();
  int row = blockIdx.x * 256 + threadIdx.x;
  if (row >= N_NODES) return;
  const float4* Fr = reinterpret_cast<const float4*>(feature + (size_t)row * 64);
#pragma unroll
  for (int k = 0; k < 2; ++k) {
    float acc[64];
#pragma unroll
    for (int o = 0; o < 64; ++o) acc[o] = 0.f;
#pragma unroll 4
    for (int i4 = 0; i4 < 16; ++i4) {
      float4 a = Fr[i4];
      float av[4] = {a.x, a.y, a.z, a.w};
#pragma unroll
      for (int u = 0; u < 4; ++u) {
        const float* Ur = &Us[(i4 * 4 + u) * 128 + k * 64];
#pragma unroll
        for (int o = 0; o < 64; ++o) acc[o] = fmaf(av[u], Ur[o], acc[o]);
      }
    }
    ushort4* Bp = reinterpret_cast<ushort4*>(B + (size_t)row * 128 + k * 64);
#pragma unroll
    for (int o4 = 0; o4 < 16; ++o4) {
      ushort4 pk;
      pk.x = f2bf(acc[o4 * 4 + 0]);
      pk.y = f2bf(acc[o4 * 4 + 1]);
      pk.z = f2bf(acc[o4 * 4 + 2]);
      pk.w = f2bf(acc[o4 * 4 + 3]);
      Bp[o4] = pk;
    }
  }
}

__global__ __launch_bounds__(256) void bhist(const int* __restrict__ edst,
                                             unsigned* __restrict__ cnt) {
  __shared__ unsigned h[NB];
  for (int i = threadIdx.x; i < NB; i += 256) h[i] = 0;
  __syncthreads();
  int stride = gridDim.x * 256;
  for (int e = blockIdx.x * 256 + threadIdx.x; e < N_EDGES; e += stride)
    atomicAdd(&h[((unsigned)edst[e]) >> BSHIFT], 1u);
  __syncthreads();
  for (int i = threadIdx.x; i < NB; i += 256)
    if (h[i]) atomicAdd(&cnt[i], h[i]);
}

__global__ __launch_bounds__(256) void bscan(const unsigned* __restrict__ cnt,
                                             unsigned* __restrict__ offs,
                                             unsigned* __restrict__ cur) {
  __shared__ unsigned sh[256];
  const int t = threadIdx.x;
  unsigned local[4];
  unsigned s = 0;
#pragma unroll
  for (int i = 0; i < 4; ++i) {
    int idx = t * 4 + i;
    local[i] = (idx < NB) ? cnt[idx] : 0u;
    s += local[i];
  }
  sh[t] = s;
  __syncthreads();
#pragma unroll
  for (int off = 1; off < 256; off <<= 1) {
    unsigned v = (t >= off) ? sh[t - off] : 0u;
    __syncthreads();
    sh[t] += v;
    __syncthreads();
  }
  unsigned run = sh[t] - s;  // exclusive
#pragma unroll
  for (int i = 0; i < 4; ++i) {
    int idx = t * 4 + i;
    if (idx < NB) { offs[idx] = run; cur[idx] = run; run += local[i]; }
  }
  if (t == 0) offs[NB] = N_EDGES;
}

__global__ __launch_bounds__(256) void bfill(const int* __restrict__ esrc,
                                             const int* __restrict__ edst,
                                             const int* __restrict__ eord,
                                             unsigned* __restrict__ cur,
                                             unsigned* __restrict__ pay) {
  int e = blockIdx.x * 256 + threadIdx.x;
  if (e >= N_EDGES) return;
  unsigned d = (unsigned)edst[e];
  unsigned pos = atomicAdd(&cur[d >> BSHIFT], 1u);
  pay[pos] = ((d & 127u) << 18) | ((unsigned)esrc[e] << 1) | (unsigned)eord[e];
}

// One block per bucket: LDS 128x64 f32 accumulator; edge-parallel bf16-row
// gather + ds_add_f32; then bias+ReLU+store+BN partials.
__global__ __launch_bounds__(256) void bgather(const unsigned* __restrict__ offs,
                                               const unsigned* __restrict__ pay,
                                               const unsigned short* __restrict__ B,
                                               const float* __restrict__ bias,
                                               float* __restrict__ out,
                                               double* __restrict__ stats) {
  __shared__ float acc[128 * 64];
  __shared__ double dred[4][64];
  const int lane = threadIdx.x & 63;
  const int w = threadIdx.x >> 6;
  const int b = blockIdx.x;

  for (int i = threadIdx.x; i < 128 * 64; i += 256) acc[i] = 0.f;
  __syncthreads();

  unsigned beg = offs[b], end = offs[b + 1];
  unsigned n = end - beg;
  unsigned per = (n + 3) >> 2;
  unsigned wb = beg + (unsigned)w * per;
  if (wb > end) wb = end;
  unsigned we = wb + per;
  if (we > end) we = end;

  unsigned e = wb;
  for (; e + 8 <= we; e += 8) {
    unsigned p[8];
#pragma unroll
    for (int j = 0; j < 8; ++j) p[j] = pay[e + j];
    unsigned short v[8];
#pragma unroll
    for (int j = 0; j < 8; ++j)
      v[j] = B[((size_t)(p[j] & 0x3FFFFu) << 6) + lane];
#pragma unroll
    for (int j = 0; j < 8; ++j)
      atomicAdd(&acc[((p[j] >> 18) << 6) + lane],
                __uint_as_float((unsigned)v[j] << 16));
  }
  for (; e < we; ++e) {
    unsigned p = pay[e];
    unsigned short v = B[((size_t)(p & 0x3FFFFu) << 6) + lane];
    atomicAdd(&acc[((p >> 18) << 6) + lane],
              __uint_as_float((unsigned)v << 16));
  }
  __syncthreads();

  const float bo = bias[lane];
  double s0 = 0.0, s1 = 0.0;
  int base = b << BSHIFT;
  for (int nl = w; nl < 128; nl += 4) {
    int ng = base + nl;
    if (ng >= N_NODES) break;
    float val = fmaxf(acc[(nl << 6) + lane] + bo, 0.f);
    out[(size_t)ng * 64 + lane] = val;
    s0 += (double)val;
    s1 += (double)val * (double)val;
  }

  dred[w][lane] = s0;
  __syncthreads();
  if (w == 0) {
    double tt = dred[0][lane] + dred[1][lane] + dred[2][lane] + dred[3][lane];
    atomicAdd(&stats[lane], tt);
  }
  __syncthreads();
  dred[w][lane] = s1;
  __syncthreads();
  if (w == 0) {
    double tt = dred[0][lane] + dred[1][lane] + dred[2][lane] + dred[3][lane];
    atomicAdd(&stats[64 + lane], tt);
  }
}

__global__ __launch_bounds__(256) void bn_apply(float* __restrict__ h,
                                                const double* __restrict__ stats,
                                                const float* __restrict__ gamma,
                                                const float* __restrict__ beta) {
  const int lane = threadIdx.x & 63;
  double mean = stats[lane] * (1.0 / N_NODES);
  double var = stats[64 + lane] * (1.0 / N_NODES) - mean * mean;
  float inv = (float)(1.0 / sqrt(var + 1e-5));
  float scale = gamma[lane] * inv;
  float shift = beta[lane] - (float)mean * scale;
  int wid = (blockIdx.x * 256 + threadIdx.x) >> 6;
  const int nw = gridDim.x * 4;
  for (int r = wid; r < N_NODES; r += nw) {
    size_t idx = (size_t)r * 64 + lane;
    h[idx] = h[idx] * scale + shift;
  }
}

extern "C" void kernel_launch(void* const* d_in, const int* in_sizes, int n_in,
                              void* d_out, int out_size, void* d_ws, size_t ws_size,
                              hipStream_t stream) {
  const float* feature = (const float*)d_in[0];
  // d_in[1] = sp_embeddings (unused)
  const float* linear = (const float*)d_in[2];
  const float* mlp_w  = (const float*)d_in[3];
  const float* mlp_b  = (const float*)d_in[4];
  const float* gamma  = (const float*)d_in[5];
  const float* beta   = (const float*)d_in[6];
  const int* esrc = (const int*)d_in[7];
  const int* edst = (const int*)d_in[8];
  const int* eord = (const int*)d_in[9];
  float* out = (float*)d_out;

  char* base = (char*)d_ws;
  unsigned*       cnt   = (unsigned*)(base);
  unsigned*       offs  = (unsigned*)(base + 3200);
  unsigned*       cur   = (unsigned*)(base + 6400);
  double*         stats = (double*)  (base + 9600);
  float*          U     = (float*)   (base + 10624);
  unsigned*       pay   = (unsigned*)(base + 43392);
  unsigned short* B     = (unsigned short*)(base + 6443392);

  hipMemsetAsync(cnt, 0, NB * 4, stream);
  hipMemsetAsync(stats, 0, 1024, stream);
  prep_U<<<1, 256, 0, stream>>>(linear, mlp_w, U);
  bhist<<<512, 256, 0, stream>>>(edst, cnt);
  bscan<<<1, 256, 0, stream>>>(cnt, offs, cur);
  bfill<<<(N_EDGES + 255) / 256, 256, 0, stream>>>(esrc, edst, eord, cur, pay);
  prep_B<<<(N_NODES + 255) / 256, 256, 0, stream>>>(feature, U, B);
  bgather<<<NB, 256, 0, stream>>>(offs, pay, B, mlp_b, out, stats);
  bn_apply<<<1024, 256, 0, stream>>>(out, stats, gamma, beta);
}

// Round 5
// 370.828 us; speedup vs baseline: 3.2740x; 3.2740x over previous
//
#include <hip/hip_runtime.h>

#define N_NODES 100000
#define N_EDGES 1600000
#define NPW 12                                   // nodes per wave in gather
#define NWAVES ((N_NODES + NPW - 1) / NPW)       // 8334
#define SCAN_CHUNK 391                            // 256 blocks * 391 >= 100000

// ws layout (bytes):
//  cnt   @ 0        : N_NODES u32
//  offs  @ 400000   : N_NODES+1 u32
//  cur   @ 800016   : N_NODES u32
//  bsum  @ 1200016  : 256 u32
//  bofs  @ 1201040  : 256 u32
//  stats @ 1202064  : 128 f64
//  U     @ 1203088  : 64x128 f32
//  pay   @ 1235856  : N_EDGES u32  (src<<1|ord, dst-sorted)
//  B     @ 7635856  : 2*N_NODES x 64 bf16 (25.6MB), row p = src*2+ord

__device__ __forceinline__ unsigned short f2bf(float x) {
  unsigned u = __float_as_uint(x);
  unsigned r = (u + 0x7FFFu + ((u >> 16) & 1u)) >> 16;
  return (unsigned short)r;
}

__global__ __launch_bounds__(256) void prep_U(const float* __restrict__ linear,
                                              const float* __restrict__ mlp_w,
                                              float* __restrict__ U) {
  int idx = blockIdx.x * 256 + threadIdx.x;  // 8192 outputs
  int o = idx & 63;
  int ki = idx >> 6;  // k*64 + i
  int k = ki >> 6, i = ki & 63;
  float acc = 0.f;
#pragma unroll 8
  for (int j = 0; j < 64; ++j)
    acc += linear[ki * 64 + j] * mlp_w[o * 64 + j];
  U[i * 128 + k * 64 + o] = acc;
}

__global__ __launch_bounds__(256) void prep_B(const float* __restrict__ feature,
                                              const float* __restrict__ U,
                                              unsigned short* __restrict__ B) {
  __shared__ float Us[64 * 128];
  for (int i = threadIdx.x; i < 64 * 128; i += 256) Us[i] = U[i];
  __syncthreads();
  int row = blockIdx.x * 256 + threadIdx.x;
  if (row >= N_NODES) return;
  const float4* Fr = reinterpret_cast<const float4*>(feature + (size_t)row * 64);
#pragma unroll
  for (int k = 0; k < 2; ++k) {
    float acc[64];
#pragma unroll
    for (int o = 0; o < 64; ++o) acc[o] = 0.f;
#pragma unroll 4
    for (int i4 = 0; i4 < 16; ++i4) {
      float4 a = Fr[i4];
      float av[4] = {a.x, a.y, a.z, a.w};
#pragma unroll
      for (int u = 0; u < 4; ++u) {
        const float* Ur = &Us[(i4 * 4 + u) * 128 + k * 64];
#pragma unroll
        for (int o = 0; o < 64; ++o) acc[o] = fmaf(av[u], Ur[o], acc[o]);
      }
    }
    // row p = row*2 + k
    ushort4* Bp = reinterpret_cast<ushort4*>(B + (((size_t)row * 2 + k) << 6));
#pragma unroll
    for (int o4 = 0; o4 < 16; ++o4) {
      ushort4 pk;
      pk.x = f2bf(acc[o4 * 4 + 0]);
      pk.y = f2bf(acc[o4 * 4 + 1]);
      pk.z = f2bf(acc[o4 * 4 + 2]);
      pk.w = f2bf(acc[o4 * 4 + 3]);
      Bp[o4] = pk;
    }
  }
}

__global__ __launch_bounds__(256) void hist(const int* __restrict__ edst,
                                            unsigned* __restrict__ cnt) {
  int e = blockIdx.x * 256 + threadIdx.x;
  if (e < N_EDGES) atomicAdd(&cnt[edst[e]], 1u);
}

__global__ __launch_bounds__(256) void scanA(const unsigned* __restrict__ cnt,
                                             unsigned* __restrict__ bsum) {
  __shared__ unsigned red[256];
  int start = blockIdx.x * SCAN_CHUNK;
  int end = min(start + SCAN_CHUNK, N_NODES);
  unsigned s = 0;
  for (int i = start + (int)threadIdx.x; i < end; i += 256) s += cnt[i];
  red[threadIdx.x] = s;
  __syncthreads();
  for (int off = 128; off > 0; off >>= 1) {
    if ((int)threadIdx.x < off) red[threadIdx.x] += red[threadIdx.x + off];
    __syncthreads();
  }
  if (threadIdx.x == 0) bsum[blockIdx.x] = red[0];
}

__global__ __launch_bounds__(256) void scanB(const unsigned* __restrict__ bsum,
                                             unsigned* __restrict__ bofs) {
  __shared__ unsigned sh[256];
  sh[threadIdx.x] = bsum[threadIdx.x];
  __syncthreads();
  if (threadIdx.x == 0) {
    unsigned run = 0;
    for (int i = 0; i < 256; ++i) { unsigned v = sh[i]; sh[i] = run; run += v; }
  }
  __syncthreads();
  bofs[threadIdx.x] = sh[threadIdx.x];
}

__global__ __launch_bounds__(256) void scanC(const unsigned* __restrict__ cnt,
                                             const unsigned* __restrict__ bofs,
                                             unsigned* __restrict__ offs,
                                             unsigned* __restrict__ cur) {
  __shared__ unsigned sh[256];
  const int t = threadIdx.x;
  int start = blockIdx.x * SCAN_CHUNK;
  int count = min(SCAN_CHUNK, N_NODES - start);
  int lo = t * 2, hi = min(count, lo + 2);
  unsigned s = 0;
  for (int i = lo; i < hi; ++i) s += cnt[start + i];
  sh[t] = s;
  __syncthreads();
#pragma unroll
  for (int off = 1; off < 256; off <<= 1) {
    unsigned v = (t >= off) ? sh[t - off] : 0u;
    __syncthreads();
    sh[t] += v;
    __syncthreads();
  }
  unsigned run = bofs[blockIdx.x] + sh[t] - s;
  for (int i = lo; i < hi; ++i) {
    offs[start + i] = run;
    cur[start + i] = run;
    run += cnt[start + i];
  }
  if (blockIdx.x == 255 && t == 0) offs[N_NODES] = N_EDGES;
}

__global__ __launch_bounds__(256) void fill(const int* __restrict__ esrc,
                                            const int* __restrict__ edst,
                                            const int* __restrict__ eord,
                                            unsigned* __restrict__ cur,
                                            unsigned* __restrict__ pay) {
  int e = blockIdx.x * 256 + threadIdx.x;
  if (e < N_EDGES) {
    int d = edst[e];
    unsigned pos = atomicAdd(&cur[d], 1u);
    pay[pos] = ((unsigned)esrc[e] << 1) | (unsigned)eord[e];
  }
}

// Streaming gather: each wave owns NPW contiguous nodes; pay reads are
// sequential; node offsets live in lanes (read via shfl); 16-deep B gathers.
__global__ __launch_bounds__(256) void gather(const unsigned* __restrict__ offs,
                                              const unsigned* __restrict__ pay,
                                              const unsigned short* __restrict__ B,
                                              const float* __restrict__ bias,
                                              float* __restrict__ out,
                                              double* __restrict__ stats) {
  __shared__ double dred[4][64];
  const int lane = threadIdx.x & 63;
  const int w = threadIdx.x >> 6;
  const float bo = bias[lane];
  double s0 = 0.0, s1 = 0.0;

  const int wid = blockIdx.x * 4 + w;
  const int n0 = wid * NPW;

  if (n0 < N_NODES) {
    const int nrem = min(NPW, N_NODES - n0);
    unsigned offv = offs[min(n0 + min(lane, NPW), N_NODES)];
    unsigned e = __shfl((int)offv, 0);
    const unsigned eEnd = __shfl((int)offv, nrem);
    int c = 0;
    unsigned next_end = __shfl((int)offv, 1);
    float sum = 0.f;

#define FLUSH()                                                        \
    do {                                                               \
      float val = fmaxf(sum + bo, 0.f);                                \
      out[((size_t)(n0 + c) << 6) + lane] = val;                       \
      s0 += (double)val;                                               \
      s1 += (double)val * (double)val;                                 \
      sum = 0.f;                                                       \
      ++c;                                                             \
      next_end = __shfl((int)offv, min(c + 1, NPW));                   \
    } while (0)

    while (e < eEnd) {
      unsigned rem = eEnd - e;
      int cnt = rem < 16u ? (int)rem : 16;
      unsigned p[16];
      unsigned short v[16];
#pragma unroll
      for (int j = 0; j < 16; ++j)
        p[j] = pay[e + (j < cnt ? j : 0)];
#pragma unroll
      for (int j = 0; j < 16; ++j)
        v[j] = B[((size_t)p[j] << 6) + lane];
#pragma unroll
      for (int j = 0; j < 16; ++j) {
        if (j < cnt) {
          while (e + (unsigned)j == next_end) FLUSH();
          sum += __uint_as_float((unsigned)v[j] << 16);
        }
      }
      e += cnt;
    }
    // flush current node's accumulated sum, then trailing (possibly empty) nodes
    for (; c < nrem; ++c) {
      float val = fmaxf(sum + bo, 0.f);
      out[((size_t)(n0 + c) << 6) + lane] = val;
      s0 += (double)val;
      s1 += (double)val * (double)val;
      sum = 0.f;
    }
#undef FLUSH
  }

  dred[w][lane] = s0;
  __syncthreads();
  if (w == 0) {
    double t = dred[0][lane] + dred[1][lane] + dred[2][lane] + dred[3][lane];
    atomicAdd(&stats[lane], t);
  }
  __syncthreads();
  dred[w][lane] = s1;
  __syncthreads();
  if (w == 0) {
    double t = dred[0][lane] + dred[1][lane] + dred[2][lane] + dred[3][lane];
    atomicAdd(&stats[64 + lane], t);
  }
}

__global__ __launch_bounds__(256) void bn_apply(float* __restrict__ h,
                                                const double* __restrict__ stats,
                                                const float* __restrict__ gamma,
                                                const float* __restrict__ beta) {
  const int lane = threadIdx.x & 63;
  double mean = stats[lane] * (1.0 / N_NODES);
  double var = stats[64 + lane] * (1.0 / N_NODES) - mean * mean;
  float inv = (float)(1.0 / sqrt(var + 1e-5));
  float scale = gamma[lane] * inv;
  float shift = beta[lane] - (float)mean * scale;
  int wid = (blockIdx.x * 256 + threadIdx.x) >> 6;
  const int nw = gridDim.x * 4;
  for (int r = wid; r < N_NODES; r += nw) {
    size_t idx = ((size_t)r << 6) + lane;
    h[idx] = h[idx] * scale + shift;
  }
}

extern "C" void kernel_launch(void* const* d_in, const int* in_sizes, int n_in,
                              void* d_out, int out_size, void* d_ws, size_t ws_size,
                              hipStream_t stream) {
  const float* feature = (const float*)d_in[0];
  // d_in[1] = sp_embeddings (unused)
  const float* linear = (const float*)d_in[2];
  const float* mlp_w  = (const float*)d_in[3];
  const float* mlp_b  = (const float*)d_in[4];
  const float* gamma  = (const float*)d_in[5];
  const float* beta   = (const float*)d_in[6];
  const int* esrc = (const int*)d_in[7];
  const int* edst = (const int*)d_in[8];
  const int* eord = (const int*)d_in[9];
  float* out = (float*)d_out;

  char* base = (char*)d_ws;
  unsigned*       cnt   = (unsigned*)(base);
  unsigned*       offs  = (unsigned*)(base + 400000);
  unsigned*       cur   = (unsigned*)(base + 800016);
  unsigned*       bsum  = (unsigned*)(base + 1200016);
  unsigned*       bofs  = (unsigned*)(base + 1201040);
  double*         stats = (double*)  (base + 1202064);
  float*          U     = (float*)   (base + 1203088);
  unsigned*       pay   = (unsigned*)(base + 1235856);
  unsigned short* B     = (unsigned short*)(base + 7635856);

  hipMemsetAsync(cnt, 0, 400000, stream);
  hipMemsetAsync(stats, 0, 1024, stream);
  prep_U<<<32, 256, 0, stream>>>(linear, mlp_w, U);
  hist<<<(N_EDGES + 255) / 256, 256, 0, stream>>>(edst, cnt);
  scanA<<<256, 256, 0, stream>>>(cnt, bsum);
  scanB<<<1, 256, 0, stream>>>(bsum, bofs);
  scanC<<<256, 256, 0, stream>>>(cnt, bofs, offs, cur);
  fill<<<(N_EDGES + 255) / 256, 256, 0, stream>>>(esrc, edst, eord, cur, pay);
  prep_B<<<(N_NODES + 255) / 256, 256, 0, stream>>>(feature, U, B);
  gather<<<(NWAVES + 3) / 4, 256, 0, stream>>>(offs, pay, B, mlp_b, out, stats);
  bn_apply<<<1024, 256, 0, stream>>>(out, stats, gamma, beta);
}

// Round 6
// 186.375 us; speedup vs baseline: 6.5143x; 1.9897x over previous
//
#include <hip/hip_runtime.h>

#define N_NODES 100000
#define N_EDGES 1600000
#define NBUCK 1563        // ceil(100000/64) buckets of 64 dst nodes
#define NBLK 128          // blocks for count/fill passes
#define PER_BLK 12500     // 128*12500 = 1.6M exact
#define MAX_BE 2048       // LDS capacity per bucket (mean 1024, +32 sigma)

// ws layout (bytes):
//  cntg  @ 0        : [128][1563] u32 (800256)  per-(block,bucket) counts -> excl offsets
//  tot   @ 800256   : 1563 u32
//  base  @ 806512   : 1564 u32                  bucket start offsets
//  stats @ 812800   : 128 f64
//  U     @ 813824   : 64x128 f32 (32768)
//  pay   @ 846592   : N_EDGES u32               (dst&63)<<18 | src<<1 | ord, bucket-sorted
//  B     @ 7246592  : 2*N_NODES x 64 bf16 (25.6MB), row p = src*2+ord

__device__ __forceinline__ unsigned short f2bf(float x) {
  unsigned u = __float_as_uint(x);
  unsigned r = (u + 0x7FFFu + ((u >> 16) & 1u)) >> 16;
  return (unsigned short)r;
}

__global__ __launch_bounds__(256) void prep_U(const float* __restrict__ linear,
                                              const float* __restrict__ mlp_w,
                                              float* __restrict__ U) {
  int idx = blockIdx.x * 256 + threadIdx.x;  // 8192 outputs
  int o = idx & 63;
  int ki = idx >> 6;
  int k = ki >> 6, i = ki & 63;
  float acc = 0.f;
#pragma unroll 8
  for (int j = 0; j < 64; ++j)
    acc += linear[ki * 64 + j] * mlp_w[o * 64 + j];
  U[i * 128 + k * 64 + o] = acc;
}

__global__ __launch_bounds__(256) void prep_B(const float* __restrict__ feature,
                                              const float* __restrict__ U,
                                              unsigned short* __restrict__ B) {
  __shared__ float Us[64 * 128];
  for (int i = threadIdx.x; i < 64 * 128; i += 256) Us[i] = U[i];
  __syncthreads();
  int row = blockIdx.x * 256 + threadIdx.x;
  if (row >= N_NODES) return;
  const float4* Fr = reinterpret_cast<const float4*>(feature + (size_t)row * 64);
#pragma unroll
  for (int k = 0; k < 2; ++k) {
    float acc[64];
#pragma unroll
    for (int o = 0; o < 64; ++o) acc[o] = 0.f;
#pragma unroll 4
    for (int i4 = 0; i4 < 16; ++i4) {
      float4 a = Fr[i4];
      float av[4] = {a.x, a.y, a.z, a.w};
#pragma unroll
      for (int u = 0; u < 4; ++u) {
        const float* Ur = &Us[(i4 * 4 + u) * 128 + k * 64];
#pragma unroll
        for (int o = 0; o < 64; ++o) acc[o] = fmaf(av[u], Ur[o], acc[o]);
      }
    }
    ushort4* Bp = reinterpret_cast<ushort4*>(B + (((size_t)row * 2 + k) << 6));
#pragma unroll
    for (int o4 = 0; o4 < 16; ++o4) {
      ushort4 pk;
      pk.x = f2bf(acc[o4 * 4 + 0]);
      pk.y = f2bf(acc[o4 * 4 + 1]);
      pk.z = f2bf(acc[o4 * 4 + 2]);
      pk.w = f2bf(acc[o4 * 4 + 3]);
      Bp[o4] = pk;
    }
  }
}

// Pass A: per-block bucket histogram over its contiguous edge slice.
__global__ __launch_bounds__(256) void countA(const int* __restrict__ edst,
                                              unsigned* __restrict__ cntg) {
  __shared__ unsigned h[NBUCK];
  for (int i = threadIdx.x; i < NBUCK; i += 256) h[i] = 0;
  __syncthreads();
  const int k = blockIdx.x;
  const int beg = k * PER_BLK, end = beg + PER_BLK;
  for (int e = beg + (int)threadIdx.x; e < end; e += 256)
    atomicAdd(&h[((unsigned)edst[e]) >> 6], 1u);
  __syncthreads();
  for (int i = threadIdx.x; i < NBUCK; i += 256)
    cntg[(size_t)k * NBUCK + i] = h[i];
}

// Transposed scan: per bucket b, exclusive scan over the 128 block counts
// (in place), plus bucket total.
__global__ __launch_bounds__(256) void scanT1(unsigned* __restrict__ cntg,
                                              unsigned* __restrict__ tot) {
  const int lane = threadIdx.x & 63;
  const int wv = threadIdx.x >> 6;
  const int b = blockIdx.x * 4 + wv;
  if (b >= NBUCK) return;
  unsigned c0 = cntg[(size_t)lane * NBUCK + b];
  unsigned c1 = cntg[(size_t)(64 + lane) * NBUCK + b];
  unsigned i0 = c0, i1 = c1;
#pragma unroll
  for (int d = 1; d < 64; d <<= 1) {
    unsigned n0 = __shfl_up(i0, d);
    unsigned n1 = __shfl_up(i1, d);
    if (lane >= d) { i0 += n0; i1 += n1; }
  }
  unsigned tot0 = __shfl(i0, 63);
  unsigned tot1 = __shfl(i1, 63);
  cntg[(size_t)lane * NBUCK + b] = i0 - c0;
  cntg[(size_t)(64 + lane) * NBUCK + b] = tot0 + i1 - c1;
  if (lane == 0) tot[b] = tot0 + tot1;
}

__global__ __launch_bounds__(256) void scanT2(const unsigned* __restrict__ tot,
                                              unsigned* __restrict__ base) {
  __shared__ unsigned sh[256];
  const int t = threadIdx.x;
  unsigned local[7];
  unsigned s = 0;
#pragma unroll
  for (int i = 0; i < 7; ++i) {
    int idx = t * 7 + i;
    local[i] = (idx < NBUCK) ? tot[idx] : 0u;
    s += local[i];
  }
  sh[t] = s;
  __syncthreads();
#pragma unroll
  for (int off = 1; off < 256; off <<= 1) {
    unsigned v = (t >= off) ? sh[t - off] : 0u;
    __syncthreads();
    sh[t] += v;
    __syncthreads();
  }
  unsigned run = sh[t] - s;
#pragma unroll
  for (int i = 0; i < 7; ++i) {
    int idx = t * 7 + i;
    if (idx < NBUCK) { base[idx] = run; run += local[i]; }
  }
  if (t == 0) base[NBUCK] = N_EDGES;
}

// Pass B: scatter payloads into block-private contiguous runs per bucket.
__global__ __launch_bounds__(256) void fillB(const int* __restrict__ esrc,
                                             const int* __restrict__ edst,
                                             const int* __restrict__ eord,
                                             const unsigned* __restrict__ cntg,
                                             const unsigned* __restrict__ base,
                                             unsigned* __restrict__ pay) {
  __shared__ unsigned curL[NBUCK];
  const int k = blockIdx.x;
  for (int i = threadIdx.x; i < NBUCK; i += 256)
    curL[i] = base[i] + cntg[(size_t)k * NBUCK + i];
  __syncthreads();
  const int beg = k * PER_BLK, end = beg + PER_BLK;
  for (int e = beg + (int)threadIdx.x; e < end; e += 256) {
    unsigned d = (unsigned)edst[e];
    unsigned pos = atomicAdd(&curL[d >> 6], 1u);
    pay[pos] = ((d & 63u) << 18) | ((unsigned)esrc[e] << 1) | (unsigned)eord[e];
  }
}

// One block per bucket: LDS counting sort by dst-low-6, then per-wave
// streaming accumulate (16 nodes/wave, 16-deep B gathers), bias+ReLU+out+BN.
__global__ __launch_bounds__(256) void bgather(const unsigned* __restrict__ base,
                                               const unsigned* __restrict__ pay,
                                               const unsigned short* __restrict__ B,
                                               const float* __restrict__ bias,
                                               float* __restrict__ out,
                                               double* __restrict__ stats) {
  __shared__ unsigned hist[64];
  __shared__ unsigned offsL[65];
  __shared__ unsigned curN[64];
  __shared__ unsigned pay_s[MAX_BE];
  __shared__ double dred[4][64];
  const int lane = threadIdx.x & 63;
  const int wv = threadIdx.x >> 6;
  const int b = blockIdx.x;
  const unsigned base0 = base[b];
  const unsigned n_e = base[b + 1] - base0;

  if (threadIdx.x < 64) hist[threadIdx.x] = 0;
  __syncthreads();
  for (unsigned i = threadIdx.x; i < n_e; i += 256)
    atomicAdd(&hist[pay[base0 + i] >> 18], 1u);
  __syncthreads();
  if (wv == 0) {
    unsigned hv = hist[lane];
    unsigned inc = hv;
#pragma unroll
    for (int d = 1; d < 64; d <<= 1) {
      unsigned n = __shfl_up(inc, d);
      if (lane >= d) inc += n;
    }
    offsL[lane + 1] = inc;
    if (lane == 0) offsL[0] = 0;
    curN[lane] = inc - hv;
  }
  __syncthreads();
  for (unsigned i = threadIdx.x; i < n_e; i += 256) {
    unsigned w = pay[base0 + i];
    unsigned pos = atomicAdd(&curN[w >> 18], 1u);
    pay_s[pos] = w;
  }
  __syncthreads();

  const float bo = bias[lane];
  double s0 = 0.0, s1 = 0.0;
  const int nb0 = (b << 6) + wv * 16;  // first node of this wave

  if (nb0 < N_NODES) {  // N_NODES%16==0 -> active wave has 16 valid nodes
    unsigned offv = (lane <= 16) ? offsL[wv * 16 + lane] : 0u;
    unsigned e = (unsigned)__shfl((int)offv, 0);
    const unsigned eEnd = (unsigned)__shfl((int)offv, 16);
    int c = 0;
    unsigned next_end = (unsigned)__shfl((int)offv, 1);
    float sum = 0.f;

#define FLUSH()                                                         \
    do {                                                                \
      float val = fmaxf(sum + bo, 0.f);                                 \
      out[((size_t)(nb0 + c) << 6) + lane] = val;                       \
      s0 += (double)val;                                                \
      s1 += (double)val * (double)val;                                  \
      sum = 0.f;                                                        \
      ++c;                                                              \
      next_end = (unsigned)__shfl((int)offv, min(c + 1, 16));           \
    } while (0)

    while (e < eEnd) {
      unsigned rem = eEnd - e;
      int cnt = rem < 16u ? (int)rem : 16;
      unsigned p[16];
      unsigned short v[16];
#pragma unroll
      for (int j = 0; j < 16; ++j)
        p[j] = pay_s[e + (j < cnt ? j : 0)];
#pragma unroll
      for (int j = 0; j < 16; ++j)
        v[j] = B[((size_t)(p[j] & 0x3FFFFu) << 6) + lane];
#pragma unroll
      for (int j = 0; j < 16; ++j) {
        if (j < cnt) {
          while (e + (unsigned)j == next_end) FLUSH();
          sum += __uint_as_float((unsigned)v[j] << 16);
        }
      }
      e += cnt;
    }
    for (; c < 16; ++c) {
      float val = fmaxf(sum + bo, 0.f);
      out[((size_t)(nb0 + c) << 6) + lane] = val;
      s0 += (double)val;
      s1 += (double)val * (double)val;
      sum = 0.f;
    }
#undef FLUSH
  }

  dred[wv][lane] = s0;
  __syncthreads();
  if (wv == 0) {
    double t = dred[0][lane] + dred[1][lane] + dred[2][lane] + dred[3][lane];
    atomicAdd(&stats[lane], t);
  }
  __syncthreads();
  dred[wv][lane] = s1;
  __syncthreads();
  if (wv == 0) {
    double t = dred[0][lane] + dred[1][lane] + dred[2][lane] + dred[3][lane];
    atomicAdd(&stats[64 + lane], t);
  }
}

__global__ __launch_bounds__(256) void bn_apply(float* __restrict__ h,
                                                const double* __restrict__ stats,
                                                const float* __restrict__ gamma,
                                                const float* __restrict__ beta) {
  const int lane = threadIdx.x & 63;
  double mean = stats[lane] * (1.0 / N_NODES);
  double var = stats[64 + lane] * (1.0 / N_NODES) - mean * mean;
  float inv = (float)(1.0 / sqrt(var + 1e-5));
  float scale = gamma[lane] * inv;
  float shift = beta[lane] - (float)mean * scale;
  int wid = (blockIdx.x * 256 + threadIdx.x) >> 6;
  const int nw = gridDim.x * 4;
  for (int r = wid; r < N_NODES; r += nw) {
    size_t idx = ((size_t)r << 6) + lane;
    h[idx] = h[idx] * scale + shift;
  }
}

extern "C" void kernel_launch(void* const* d_in, const int* in_sizes, int n_in,
                              void* d_out, int out_size, void* d_ws, size_t ws_size,
                              hipStream_t stream) {
  const float* feature = (const float*)d_in[0];
  // d_in[1] = sp_embeddings (unused)
  const float* linear = (const float*)d_in[2];
  const float* mlp_w  = (const float*)d_in[3];
  const float* mlp_b  = (const float*)d_in[4];
  const float* gamma  = (const float*)d_in[5];
  const float* beta   = (const float*)d_in[6];
  const int* esrc = (const int*)d_in[7];
  const int* edst = (const int*)d_in[8];
  const int* eord = (const int*)d_in[9];
  float* out = (float*)d_out;

  char* basep = (char*)d_ws;
  unsigned*       cntg  = (unsigned*)(basep);
  unsigned*       tot   = (unsigned*)(basep + 800256);
  unsigned*       base  = (unsigned*)(basep + 806512);
  double*         stats = (double*)  (basep + 812800);
  float*          U     = (float*)   (basep + 813824);
  unsigned*       pay   = (unsigned*)(basep + 846592);
  unsigned short* B     = (unsigned short*)(basep + 7246592);

  hipMemsetAsync(stats, 0, 1024, stream);
  prep_U<<<32, 256, 0, stream>>>(linear, mlp_w, U);
  countA<<<NBLK, 256, 0, stream>>>(edst, cntg);
  scanT1<<<(NBUCK + 3) / 4, 256, 0, stream>>>(cntg, tot);
  scanT2<<<1, 256, 0, stream>>>(tot, base);
  fillB<<<NBLK, 256, 0, stream>>>(esrc, edst, eord, cntg, base, pay);
  prep_B<<<(N_NODES + 255) / 256, 256, 0, stream>>>(feature, U, B);
  bgather<<<NBUCK, 256, 0, stream>>>(base, pay, B, mlp_b, out, stats);
  bn_apply<<<1024, 256, 0, stream>>>(out, stats, gamma, beta);
}

// Round 7
// 178.896 us; speedup vs baseline: 6.7866x; 1.0418x over previous
//
#include <hip/hip_runtime.h>

#define N_NODES 100000
#define N_EDGES 1600000
#define NBUCK 1563        // ceil(100000/64) buckets of 64 dst nodes
#define NBLK 128          // blocks for count/fill passes
#define PER_BLK 12500     // 128*12500 = 1.6M exact
#define MAX_BE 2048       // LDS capacity per bucket (mean 1024, max ~1140)

// ws layout (bytes):
//  cntg  @ 0        : [128][1563] u32 (800256)
//  tot   @ 800256   : 1563 u32
//  base  @ 806512   : 1564 u32
//  stats @ 812800   : 128 f64
//  U     @ 813824   : 64x128 f32 (32768)
//  pay   @ 846592   : N_EDGES u32   (dst&63)<<18 | src<<1 | ord, bucket-sorted
//  B     @ 7246592  : 2*N_NODES x 64 bf16 (25.6MB), row p = src*2+ord

__device__ __forceinline__ unsigned short f2bf(float x) {
  unsigned u = __float_as_uint(x);
  unsigned r = (u + 0x7FFFu + ((u >> 16) & 1u)) >> 16;
  return (unsigned short)r;
}

__global__ __launch_bounds__(256) void prep_U(const float* __restrict__ linear,
                                              const float* __restrict__ mlp_w,
                                              float* __restrict__ U) {
  int idx = blockIdx.x * 256 + threadIdx.x;  // 8192 outputs
  int o = idx & 63;
  int ki = idx >> 6;
  int k = ki >> 6, i = ki & 63;
  float acc = 0.f;
#pragma unroll 8
  for (int j = 0; j < 64; ++j)
    acc += linear[ki * 64 + j] * mlp_w[o * 64 + j];
  U[i * 128 + k * 64 + o] = acc;
}

__global__ __launch_bounds__(256) void prep_B(const float* __restrict__ feature,
                                              const float* __restrict__ U,
                                              unsigned short* __restrict__ B) {
  __shared__ float Us[64 * 128];
  for (int i = threadIdx.x; i < 64 * 128; i += 256) Us[i] = U[i];
  __syncthreads();
  int row = blockIdx.x * 256 + threadIdx.x;
  if (row >= N_NODES) return;
  const float4* Fr = reinterpret_cast<const float4*>(feature + (size_t)row * 64);
#pragma unroll
  for (int k = 0; k < 2; ++k) {
    float acc[64];
#pragma unroll
    for (int o = 0; o < 64; ++o) acc[o] = 0.f;
#pragma unroll 4
    for (int i4 = 0; i4 < 16; ++i4) {
      float4 a = Fr[i4];
      float av[4] = {a.x, a.y, a.z, a.w};
#pragma unroll
      for (int u = 0; u < 4; ++u) {
        const float* Ur = &Us[(i4 * 4 + u) * 128 + k * 64];
#pragma unroll
        for (int o = 0; o < 64; ++o) acc[o] = fmaf(av[u], Ur[o], acc[o]);
      }
    }
    ushort4* Bp = reinterpret_cast<ushort4*>(B + (((size_t)row * 2 + k) << 6));
#pragma unroll
    for (int o4 = 0; o4 < 16; ++o4) {
      ushort4 pk;
      pk.x = f2bf(acc[o4 * 4 + 0]);
      pk.y = f2bf(acc[o4 * 4 + 1]);
      pk.z = f2bf(acc[o4 * 4 + 2]);
      pk.w = f2bf(acc[o4 * 4 + 3]);
      Bp[o4] = pk;
    }
  }
}

__global__ __launch_bounds__(256) void countA(const int* __restrict__ edst,
                                              unsigned* __restrict__ cntg) {
  __shared__ unsigned h[NBUCK];
  for (int i = threadIdx.x; i < NBUCK; i += 256) h[i] = 0;
  __syncthreads();
  const int k = blockIdx.x;
  const int beg = k * PER_BLK, end = beg + PER_BLK;
  for (int e = beg + (int)threadIdx.x; e < end; e += 256)
    atomicAdd(&h[((unsigned)edst[e]) >> 6], 1u);
  __syncthreads();
  for (int i = threadIdx.x; i < NBUCK; i += 256)
    cntg[(size_t)k * NBUCK + i] = h[i];
}

__global__ __launch_bounds__(256) void scanT1(unsigned* __restrict__ cntg,
                                              unsigned* __restrict__ tot) {
  const int lane = threadIdx.x & 63;
  const int wv = threadIdx.x >> 6;
  const int b = blockIdx.x * 4 + wv;
  if (b >= NBUCK) return;
  unsigned c0 = cntg[(size_t)lane * NBUCK + b];
  unsigned c1 = cntg[(size_t)(64 + lane) * NBUCK + b];
  unsigned i0 = c0, i1 = c1;
#pragma unroll
  for (int d = 1; d < 64; d <<= 1) {
    unsigned n0 = __shfl_up(i0, d);
    unsigned n1 = __shfl_up(i1, d);
    if (lane >= d) { i0 += n0; i1 += n1; }
  }
  unsigned tot0 = __shfl(i0, 63);
  unsigned tot1 = __shfl(i1, 63);
  cntg[(size_t)lane * NBUCK + b] = i0 - c0;
  cntg[(size_t)(64 + lane) * NBUCK + b] = tot0 + i1 - c1;
  if (lane == 0) tot[b] = tot0 + tot1;
}

__global__ __launch_bounds__(256) void scanT2(const unsigned* __restrict__ tot,
                                              unsigned* __restrict__ base) {
  __shared__ unsigned sh[256];
  const int t = threadIdx.x;
  unsigned local[7];
  unsigned s = 0;
#pragma unroll
  for (int i = 0; i < 7; ++i) {
    int idx = t * 7 + i;
    local[i] = (idx < NBUCK) ? tot[idx] : 0u;
    s += local[i];
  }
  sh[t] = s;
  __syncthreads();
#pragma unroll
  for (int off = 1; off < 256; off <<= 1) {
    unsigned v = (t >= off) ? sh[t - off] : 0u;
    __syncthreads();
    sh[t] += v;
    __syncthreads();
  }
  unsigned run = sh[t] - s;
#pragma unroll
  for (int i = 0; i < 7; ++i) {
    int idx = t * 7 + i;
    if (idx < NBUCK) { base[idx] = run; run += local[i]; }
  }
  if (t == 0) base[NBUCK] = N_EDGES;
}

__global__ __launch_bounds__(256) void fillB(const int* __restrict__ esrc,
                                             const int* __restrict__ edst,
                                             const int* __restrict__ eord,
                                             const unsigned* __restrict__ cntg,
                                             const unsigned* __restrict__ base,
                                             unsigned* __restrict__ pay) {
  __shared__ unsigned curL[NBUCK];
  const int k = blockIdx.x;
  for (int i = threadIdx.x; i < NBUCK; i += 256)
    curL[i] = base[i] + cntg[(size_t)k * NBUCK + i];
  __syncthreads();
  const int beg = k * PER_BLK, end = beg + PER_BLK;
  for (int e = beg + (int)threadIdx.x; e < end; e += 256) {
    unsigned d = (unsigned)edst[e];
    unsigned pos = atomicAdd(&curL[d >> 6], 1u);
    pay[pos] = ((d & 63u) << 18) | ((unsigned)esrc[e] << 1) | (unsigned)eord[e];
  }
}

// One block per bucket: LDS counting-sort by dst-low-6, then 16-lane node
// groups: each group owns 4 nodes, gathers u64 (4 bf16 ch) per lane per edge.
__global__ __launch_bounds__(256) void bgather(const unsigned* __restrict__ base,
                                               const unsigned* __restrict__ pay,
                                               const unsigned short* __restrict__ B,
                                               const float* __restrict__ bias,
                                               float* __restrict__ out,
                                               double* __restrict__ stats) {
  __shared__ unsigned hist[64];
  __shared__ unsigned offsL[65];
  __shared__ unsigned curN[64];
  __shared__ unsigned pay_s[MAX_BE];
  __shared__ double dd0[4][64];
  __shared__ double dd1[4][64];
  const int tid = threadIdx.x;
  const int lane = tid & 63;
  const int wv = tid >> 6;
  const int b = blockIdx.x;
  const unsigned base0 = base[b];
  const unsigned n_e = base[b + 1] - base0;

  if (tid < 64) hist[tid] = 0;
  __syncthreads();
  for (unsigned i = tid; i < n_e; i += 256)
    atomicAdd(&hist[pay[base0 + i] >> 18], 1u);
  __syncthreads();
  if (wv == 0) {
    unsigned hv = hist[lane];
    unsigned inc = hv;
#pragma unroll
    for (int d = 1; d < 64; d <<= 1) {
      unsigned n = __shfl_up(inc, d);
      if (lane >= d) inc += n;
    }
    offsL[lane + 1] = inc;
    if (lane == 0) offsL[0] = 0;
    curN[lane] = inc - hv;
  }
  __syncthreads();
  for (unsigned i = tid; i < n_e; i += 256) {
    unsigned w = pay[base0 + i];
    unsigned pos = atomicAdd(&curN[w >> 18], 1u);
    pay_s[pos] = w;
  }
  __syncthreads();

  // ---- 16-lane groups: group g owns nodes g*4..g*4+3; lane covers 4 channels
  const int g = tid >> 4;        // 0..15
  const int sl = tid & 15;       // sub-lane
  const int c0 = sl << 2;        // first channel
  const float4 bo4 = *reinterpret_cast<const float4*>(bias + c0);
  double s0[4] = {0, 0, 0, 0}, s1[4] = {0, 0, 0, 0};

#pragma unroll
  for (int i = 0; i < 4; ++i) {
    const int nl = (g << 2) + i;
    const int ng = (b << 6) + nl;
    unsigned e = offsL[nl];
    const unsigned e1 = offsL[nl + 1];
    float s[4] = {0.f, 0.f, 0.f, 0.f};
    while (e < e1) {
      unsigned rem = e1 - e;
      int cnt = rem < 8u ? (int)rem : 8;
      unsigned p[8];
      uint2 v[8];
#pragma unroll
      for (int j = 0; j < 8; ++j)
        p[j] = pay_s[e + (j < cnt ? (unsigned)j : 0u)];
#pragma unroll
      for (int j = 0; j < 8; ++j)
        v[j] = *reinterpret_cast<const uint2*>(
            B + (((size_t)(p[j] & 0x3FFFFu)) << 6) + c0);
#pragma unroll
      for (int j = 0; j < 8; ++j) {
        if (j < cnt) {
          s[0] += __uint_as_float(v[j].x << 16);
          s[1] += __uint_as_float(v[j].x & 0xFFFF0000u);
          s[2] += __uint_as_float(v[j].y << 16);
          s[3] += __uint_as_float(v[j].y & 0xFFFF0000u);
        }
      }
      e += cnt;
    }
    if (ng < N_NODES) {
      float4 r;
      r.x = fmaxf(s[0] + bo4.x, 0.f);
      r.y = fmaxf(s[1] + bo4.y, 0.f);
      r.z = fmaxf(s[2] + bo4.z, 0.f);
      r.w = fmaxf(s[3] + bo4.w, 0.f);
      *reinterpret_cast<float4*>(out + ((size_t)ng << 6) + c0) = r;
      s0[0] += (double)r.x; s1[0] += (double)r.x * (double)r.x;
      s0[1] += (double)r.y; s1[1] += (double)r.y * (double)r.y;
      s0[2] += (double)r.z; s1[2] += (double)r.z * (double)r.z;
      s0[3] += (double)r.w; s1[3] += (double)r.w * (double)r.w;
    }
  }

  // stats reduce: lanes {sl, sl+16, sl+32, sl+48} hold same channels
#pragma unroll
  for (int q = 0; q < 4; ++q) {
    double v0 = s0[q], v1 = s1[q];
    v0 += __shfl_xor(v0, 16); v0 += __shfl_xor(v0, 32);
    v1 += __shfl_xor(v1, 16); v1 += __shfl_xor(v1, 32);
    s0[q] = v0; s1[q] = v1;
  }
  if ((lane & 48) == 0) {
#pragma unroll
    for (int q = 0; q < 4; ++q) {
      dd0[wv][c0 + q] = s0[q];
      dd1[wv][c0 + q] = s1[q];
    }
  }
  __syncthreads();
  if (tid < 64) {
    double t0 = dd0[0][tid] + dd0[1][tid] + dd0[2][tid] + dd0[3][tid];
    double t1 = dd1[0][tid] + dd1[1][tid] + dd1[2][tid] + dd1[3][tid];
    atomicAdd(&stats[tid], t0);
    atomicAdd(&stats[64 + tid], t1);
  }
}

__global__ __launch_bounds__(256) void bn_apply(float* __restrict__ h,
                                                const double* __restrict__ stats,
                                                const float* __restrict__ gamma,
                                                const float* __restrict__ beta) {
  const int lane = threadIdx.x & 63;
  double mean = stats[lane] * (1.0 / N_NODES);
  double var = stats[64 + lane] * (1.0 / N_NODES) - mean * mean;
  float inv = (float)(1.0 / sqrt(var + 1e-5));
  float scale = gamma[lane] * inv;
  float shift = beta[lane] - (float)mean * scale;
  int wid = (blockIdx.x * 256 + threadIdx.x) >> 6;
  const int nw = gridDim.x * 4;
  for (int r = wid; r < N_NODES; r += nw) {
    size_t idx = ((size_t)r << 6) + lane;
    h[idx] = h[idx] * scale + shift;
  }
}

extern "C" void kernel_launch(void* const* d_in, const int* in_sizes, int n_in,
                              void* d_out, int out_size, void* d_ws, size_t ws_size,
                              hipStream_t stream) {
  const float* feature = (const float*)d_in[0];
  // d_in[1] = sp_embeddings (unused)
  const float* linear = (const float*)d_in[2];
  const float* mlp_w  = (const float*)d_in[3];
  const float* mlp_b  = (const float*)d_in[4];
  const float* gamma  = (const float*)d_in[5];
  const float* beta   = (const float*)d_in[6];
  const int* esrc = (const int*)d_in[7];
  const int* edst = (const int*)d_in[8];
  const int* eord = (const int*)d_in[9];
  float* out = (float*)d_out;

  char* basep = (char*)d_ws;
  unsigned*       cntg  = (unsigned*)(basep);
  unsigned*       tot   = (unsigned*)(basep + 800256);
  unsigned*       base  = (unsigned*)(basep + 806512);
  double*         stats = (double*)  (basep + 812800);
  float*          U     = (float*)   (basep + 813824);
  unsigned*       pay   = (unsigned*)(basep + 846592);
  unsigned short* B     = (unsigned short*)(basep + 7246592);

  hipMemsetAsync(stats, 0, 1024, stream);
  prep_U<<<32, 256, 0, stream>>>(linear, mlp_w, U);
  countA<<<NBLK, 256, 0, stream>>>(edst, cntg);
  scanT1<<<(NBUCK + 3) / 4, 256, 0, stream>>>(cntg, tot);
  scanT2<<<1, 256, 0, stream>>>(tot, base);
  fillB<<<NBLK, 256, 0, stream>>>(esrc, edst, eord, cntg, base, pay);
  prep_B<<<(N_NODES + 255) / 256, 256, 0, stream>>>(feature, U, B);
  bgather<<<NBUCK, 256, 0, stream>>>(base, pay, B, mlp_b, out, stats);
  bn_apply<<<1024, 256, 0, stream>>>(out, stats, gamma, beta);
}

// Round 9
// 168.602 us; speedup vs baseline: 7.2010x; 1.0611x over previous
//
#include <hip/hip_runtime.h>

#define N_NODES 100000
#define N_EDGES 1600000
#define NBUCK 1563        // ceil(100000/64) buckets of 64 dst nodes
#define NBLK 256          // blocks for count/fill passes
#define PER_BLK 6250      // 256*6250 = 1.6M exact
#define MAX_BE 2048       // LDS capacity per bucket (mean 1024, max ~1140)

// ws layout (bytes):
//  cntg  @ 0        : [256][1563] u32 (1600512)
//  tot   @ 1600512  : 1563 u32
//  base  @ 1606768  : 1564 u32
//  stats @ 1613056  : 128 f64
//  U     @ 1614080  : 64x128 f32 (32768)
//  pay   @ 1646848  : N_EDGES u32   (dst&63)<<18 | src<<1 | ord, bucket-sorted
//  B     @ 8046848  : 2*N_NODES x 64 bf16 (25.6MB), row p = src*2+ord

__device__ __forceinline__ unsigned short f2bf(float x) {
  unsigned u = __float_as_uint(x);
  unsigned r = (u + 0x7FFFu + ((u >> 16) & 1u)) >> 16;
  return (unsigned short)r;
}

__global__ __launch_bounds__(256) void prep_U(const float* __restrict__ linear,
                                              const float* __restrict__ mlp_w,
                                              float* __restrict__ U) {
  int idx = blockIdx.x * 256 + threadIdx.x;  // 8192 outputs
  int o = idx & 63;
  int ki = idx >> 6;
  int k = ki >> 6, i = ki & 63;
  float acc = 0.f;
#pragma unroll 8
  for (int j = 0; j < 64; ++j)
    acc += linear[ki * 64 + j] * mlp_w[o * 64 + j];
  U[i * 128 + k * 64 + o] = acc;
}

// 2 rows per thread: LDS Us reads amortized over both rows.
__global__ __launch_bounds__(256) void prep_B(const float* __restrict__ feature,
                                              const float* __restrict__ U,
                                              unsigned short* __restrict__ B) {
  __shared__ float Us[64 * 128];
  for (int i = threadIdx.x; i < 64 * 128; i += 256) Us[i] = U[i];
  __syncthreads();
  const int ra = blockIdx.x * 512 + threadIdx.x;
  const int rb = ra + 256;
  const bool va = ra < N_NODES, vb = rb < N_NODES;
  const float4* Fa = reinterpret_cast<const float4*>(feature + (size_t)(va ? ra : 0) * 64);
  const float4* Fb = reinterpret_cast<const float4*>(feature + (size_t)(vb ? rb : 0) * 64);
#pragma unroll
  for (int k = 0; k < 2; ++k) {
    float acc0[64], acc1[64];
#pragma unroll
    for (int o = 0; o < 64; ++o) { acc0[o] = 0.f; acc1[o] = 0.f; }
#pragma unroll 2
    for (int i4 = 0; i4 < 16; ++i4) {
      float4 a = Fa[i4];
      float4 cc = Fb[i4];
      float av[4] = {a.x, a.y, a.z, a.w};
      float cv[4] = {cc.x, cc.y, cc.z, cc.w};
#pragma unroll
      for (int u = 0; u < 4; ++u) {
        const float* Ur = &Us[(i4 * 4 + u) * 128 + k * 64];
#pragma unroll
        for (int o = 0; o < 64; ++o) {
          float w = Ur[o];
          acc0[o] = fmaf(av[u], w, acc0[o]);
          acc1[o] = fmaf(cv[u], w, acc1[o]);
        }
      }
    }
    if (va) {
      ushort4* Bp = reinterpret_cast<ushort4*>(B + (((size_t)ra * 2 + k) << 6));
#pragma unroll
      for (int o4 = 0; o4 < 16; ++o4) {
        ushort4 pk;
        pk.x = f2bf(acc0[o4 * 4 + 0]);
        pk.y = f2bf(acc0[o4 * 4 + 1]);
        pk.z = f2bf(acc0[o4 * 4 + 2]);
        pk.w = f2bf(acc0[o4 * 4 + 3]);
        Bp[o4] = pk;
      }
    }
    if (vb) {
      ushort4* Bp = reinterpret_cast<ushort4*>(B + (((size_t)rb * 2 + k) << 6));
#pragma unroll
      for (int o4 = 0; o4 < 16; ++o4) {
        ushort4 pk;
        pk.x = f2bf(acc1[o4 * 4 + 0]);
        pk.y = f2bf(acc1[o4 * 4 + 1]);
        pk.z = f2bf(acc1[o4 * 4 + 2]);
        pk.w = f2bf(acc1[o4 * 4 + 3]);
        Bp[o4] = pk;
      }
    }
  }
}

__global__ __launch_bounds__(512) void countA(const int* __restrict__ edst,
                                              unsigned* __restrict__ cntg) {
  __shared__ unsigned h[NBUCK];
  for (int i = threadIdx.x; i < NBUCK; i += 512) h[i] = 0;
  __syncthreads();
  const int k = blockIdx.x;
  const int beg = k * PER_BLK, end = beg + PER_BLK;
  for (int e = beg + (int)threadIdx.x; e < end; e += 512)
    atomicAdd(&h[((unsigned)edst[e]) >> 6], 1u);
  __syncthreads();
  for (int i = threadIdx.x; i < NBUCK; i += 512)
    cntg[(size_t)k * NBUCK + i] = h[i];
}

// Per bucket b: exclusive scan over the 256 block counts (lane covers 4).
__global__ __launch_bounds__(256) void scanT1(unsigned* __restrict__ cntg,
                                              unsigned* __restrict__ tot) {
  const int lane = threadIdx.x & 63;
  const int wv = threadIdx.x >> 6;
  const int b = blockIdx.x * 4 + wv;
  if (b >= NBUCK) return;
  unsigned c[4];
  unsigned lsum = 0;
#pragma unroll
  for (int j = 0; j < 4; ++j) {
    c[j] = cntg[(size_t)(lane * 4 + j) * NBUCK + b];
    lsum += c[j];
  }
  unsigned inc = lsum;
#pragma unroll
  for (int d = 1; d < 64; d <<= 1) {
    unsigned n = __shfl_up(inc, d);
    if (lane >= d) inc += n;
  }
  unsigned run = inc - lsum;  // exclusive over lanes
#pragma unroll
  for (int j = 0; j < 4; ++j) {
    cntg[(size_t)(lane * 4 + j) * NBUCK + b] = run;
    run += c[j];
  }
  unsigned total = __shfl(inc, 63);
  if (lane == 0) tot[b] = total;
}

__global__ __launch_bounds__(256) void scanT2(const unsigned* __restrict__ tot,
                                              unsigned* __restrict__ base) {
  __shared__ unsigned sh[256];
  const int t = threadIdx.x;
  unsigned local[7];
  unsigned s = 0;
#pragma unroll
  for (int i = 0; i < 7; ++i) {
    int idx = t * 7 + i;
    local[i] = (idx < NBUCK) ? tot[idx] : 0u;
    s += local[i];
  }
  sh[t] = s;
  __syncthreads();
#pragma unroll
  for (int off = 1; off < 256; off <<= 1) {
    unsigned v = (t >= off) ? sh[t - off] : 0u;
    __syncthreads();
    sh[t] += v;
    __syncthreads();
  }
  unsigned run = sh[t] - s;
#pragma unroll
  for (int i = 0; i < 7; ++i) {
    int idx = t * 7 + i;
    if (idx < NBUCK) { base[idx] = run; run += local[i]; }
  }
  if (t == 0) base[NBUCK] = N_EDGES;
}

__global__ __launch_bounds__(512) void fillB(const int* __restrict__ esrc,
                                             const int* __restrict__ edst,
                                             const int* __restrict__ eord,
                                             const unsigned* __restrict__ cntg,
                                             const unsigned* __restrict__ base,
                                             unsigned* __restrict__ pay) {
  __shared__ unsigned curL[NBUCK];
  const int k = blockIdx.x;
  for (int i = threadIdx.x; i < NBUCK; i += 512)
    curL[i] = base[i] + cntg[(size_t)k * NBUCK + i];
  __syncthreads();
  const int beg = k * PER_BLK, end = beg + PER_BLK;
  for (int e = beg + (int)threadIdx.x; e < end; e += 512) {
    unsigned d = (unsigned)edst[e];
    unsigned pos = atomicAdd(&curL[d >> 6], 1u);
    pay[pos] = ((d & 63u) << 18) | ((unsigned)esrc[e] << 1) | (unsigned)eord[e];
  }
}

// One block per bucket: LDS counting-sort by dst-low-6, then 16-lane node
// groups: each group owns 4 nodes, gathers u64 (4 bf16 ch) per lane per edge.
__global__ __launch_bounds__(256) void bgather(const unsigned* __restrict__ base,
                                               const unsigned* __restrict__ pay,
                                               const unsigned short* __restrict__ B,
                                               const float* __restrict__ bias,
                                               float* __restrict__ out,
                                               double* __restrict__ stats) {
  __shared__ unsigned hist[64];
  __shared__ unsigned offsL[65];
  __shared__ unsigned curN[64];
  __shared__ unsigned pay_s[MAX_BE];
  __shared__ double dd0[4][64];
  __shared__ double dd1[4][64];
  const int tid = threadIdx.x;
  const int lane = tid & 63;
  const int wv = tid >> 6;
  const int b = blockIdx.x;
  const unsigned base0 = base[b];
  const unsigned n_e = base[b + 1] - base0;

  if (tid < 64) hist[tid] = 0;
  __syncthreads();
  for (unsigned i = tid; i < n_e; i += 256)
    atomicAdd(&hist[pay[base0 + i] >> 18], 1u);
  __syncthreads();
  if (wv == 0) {
    unsigned hv = hist[lane];
    unsigned inc = hv;
#pragma unroll
    for (int d = 1; d < 64; d <<= 1) {
      unsigned n = __shfl_up(inc, d);
      if (lane >= d) inc += n;
    }
    offsL[lane + 1] = inc;
    if (lane == 0) offsL[0] = 0;
    curN[lane] = inc - hv;
  }
  __syncthreads();
  for (unsigned i = tid; i < n_e; i += 256) {
    unsigned w = pay[base0 + i];
    unsigned pos = atomicAdd(&curN[w >> 18], 1u);
    pay_s[pos] = w;
  }
  __syncthreads();

  const int g = tid >> 4;        // 0..15
  const int sl = tid & 15;       // sub-lane
  const int c0 = sl << 2;        // first channel
  const float4 bo4 = *reinterpret_cast<const float4*>(bias + c0);
  double s0[4] = {0, 0, 0, 0}, s1[4] = {0, 0, 0, 0};

#pragma unroll
  for (int i = 0; i < 4; ++i) {
    const int nl = (g << 2) + i;
    const int ng = (b << 6) + nl;
    unsigned e = offsL[nl];
    const unsigned e1 = offsL[nl + 1];
    float s[4] = {0.f, 0.f, 0.f, 0.f};
    while (e < e1) {
      unsigned rem = e1 - e;
      int cnt = rem < 8u ? (int)rem : 8;
      unsigned p[8];
      uint2 v[8];
#pragma unroll
      for (int j = 0; j < 8; ++j)
        p[j] = pay_s[e + (j < cnt ? (unsigned)j : 0u)];
#pragma unroll
      for (int j = 0; j < 8; ++j)
        v[j] = *reinterpret_cast<const uint2*>(
            B + (((size_t)(p[j] & 0x3FFFFu)) << 6) + c0);
#pragma unroll
      for (int j = 0; j < 8; ++j) {
        if (j < cnt) {
          s[0] += __uint_as_float(v[j].x << 16);
          s[1] += __uint_as_float(v[j].x & 0xFFFF0000u);
          s[2] += __uint_as_float(v[j].y << 16);
          s[3] += __uint_as_float(v[j].y & 0xFFFF0000u);
        }
      }
      e += cnt;
    }
    if (ng < N_NODES) {
      float4 r;
      r.x = fmaxf(s[0] + bo4.x, 0.f);
      r.y = fmaxf(s[1] + bo4.y, 0.f);
      r.z = fmaxf(s[2] + bo4.z, 0.f);
      r.w = fmaxf(s[3] + bo4.w, 0.f);
      *reinterpret_cast<float4*>(out + ((size_t)ng << 6) + c0) = r;
      s0[0] += (double)r.x; s1[0] += (double)r.x * (double)r.x;
      s0[1] += (double)r.y; s1[1] += (double)r.y * (double)r.y;
      s0[2] += (double)r.z; s1[2] += (double)r.z * (double)r.z;
      s0[3] += (double)r.w; s1[3] += (double)r.w * (double)r.w;
    }
  }

#pragma unroll
  for (int q = 0; q < 4; ++q) {
    double v0 = s0[q], v1 = s1[q];
    v0 += __shfl_xor(v0, 16); v0 += __shfl_xor(v0, 32);
    v1 += __shfl_xor(v1, 16); v1 += __shfl_xor(v1, 32);
    s0[q] = v0; s1[q] = v1;
  }
  if ((lane & 48) == 0) {
#pragma unroll
    for (int q = 0; q < 4; ++q) {
      dd0[wv][c0 + q] = s0[q];
      dd1[wv][c0 + q] = s1[q];
    }
  }
  __syncthreads();
  if (tid < 64) {
    double t0 = dd0[0][tid] + dd0[1][tid] + dd0[2][tid] + dd0[3][tid];
    double t1 = dd1[0][tid] + dd1[1][tid] + dd1[2][tid] + dd1[3][tid];
    atomicAdd(&stats[tid], t0);
    atomicAdd(&stats[64 + tid], t1);
  }
}

__global__ __launch_bounds__(256) void bn_apply(float* __restrict__ h,
                                                const double* __restrict__ stats,
                                                const float* __restrict__ gamma,
                                                const float* __restrict__ beta) {
  const int lane = threadIdx.x & 63;
  double mean = stats[lane] * (1.0 / N_NODES);
  double var = stats[64 + lane] * (1.0 / N_NODES) - mean * mean;
  float inv = (float)(1.0 / sqrt(var + 1e-5));
  float scale = gamma[lane] * inv;
  float shift = beta[lane] - (float)mean * scale;
  int wid = (blockIdx.x * 256 + threadIdx.x) >> 6;
  const int nw = gridDim.x * 4;
  for (int r = wid; r < N_NODES; r += nw) {
    size_t idx = ((size_t)r << 6) + lane;
    h[idx] = h[idx] * scale + shift;
  }
}

extern "C" void kernel_launch(void* const* d_in, const int* in_sizes, int n_in,
                              void* d_out, int out_size, void* d_ws, size_t ws_size,
                              hipStream_t stream) {
  const float* feature = (const float*)d_in[0];
  // d_in[1] = sp_embeddings (unused)
  const float* linear = (const float*)d_in[2];
  const float* mlp_w  = (const float*)d_in[3];
  const float* mlp_b  = (const float*)d_in[4];
  const float* gamma  = (const float*)d_in[5];
  const float* beta   = (const float*)d_in[6];
  const int* esrc = (const int*)d_in[7];
  const int* edst = (const int*)d_in[8];
  const int* eord = (const int*)d_in[9];
  float* out = (float*)d_out;

  char* basep = (char*)d_ws;
  unsigned*       cntg  = (unsigned*)(basep);
  unsigned*       tot   = (unsigned*)(basep + 1600512);
  unsigned*       base  = (unsigned*)(basep + 1606768);
  double*         stats = (double*)  (basep + 1613056);
  float*          U     = (float*)   (basep + 1614080);
  unsigned*       pay   = (unsigned*)(basep + 1646848);
  unsigned short* B     = (unsigned short*)(basep + 8046848);

  (void)hipMemsetAsync(stats, 0, 1024, stream);
  prep_U<<<32, 256, 0, stream>>>(linear, mlp_w, U);
  countA<<<NBLK, 512, 0, stream>>>(edst, cntg);
  scanT1<<<(NBUCK + 3) / 4, 256, 0, stream>>>(cntg, tot);
  scanT2<<<1, 256, 0, stream>>>(tot, base);
  fillB<<<NBLK, 512, 0, stream>>>(esrc, edst, eord, cntg, base, pay);
  prep_B<<<(N_NODES + 511) / 512, 256, 0, stream>>>(feature, U, B);
  bgather<<<NBUCK, 256, 0, stream>>>(base, pay, B, mlp_b, out, stats);
  bn_apply<<<1024, 256, 0, stream>>>(out, stats, gamma, beta);
}